// Round 6
// baseline (276.015 us; speedup 1.0000x reference)
//
#include <hip/hip_runtime.h>
#include <hip/hip_bf16.h>
#include <hip/hip_fp16.h>

// AGNN 2-layer encoder: N=50000 nodes, E=850000 edges (w/ self-loops), D=H=128.
// R6: un-fused convert (padded-counter theory gets standalone measurement),
// agg prefetch depth 2. Pipeline: convert(+detect+hist+rank) -> scan ->
// scatter -> [gemm+rownorm(fp16) -> attn-agg(+relu)] x2.

#define FDIM 128
#define SCAN_CHUNK 2048   // 256 threads x 8 elems
#define CSTRIDE 32        // ints per histogram counter (one 128B line each)

// ------- convert edges -> int32, padded histogram + within-dst rank --------
// dtype detect fused: int64 <=> odd 32-bit words of first 32 entries all 0.
__global__ __launch_bounds__(256) void convert_count_kernel(
    const void* __restrict__ ei, int E,
    int* __restrict__ src32, int* __restrict__ dst32,
    int* __restrict__ rank, int* __restrict__ counts) {
  const int* eii = (const int*)ei;
  int lane = threadIdx.x & 63;
  int ok = (lane < 32) ? (eii[2 * lane + 1] == 0) : 1;
  bool is64 = (__ballot(ok) == ~0ull);

  int e = blockIdx.x * 256 + threadIdx.x;
  if (e >= E) return;
  int s, d;
  if (is64) {
    const long long* p = (const long long*)ei;
    s = (int)p[e]; d = (int)p[E + e];
  } else {
    s = eii[e]; d = eii[E + e];
  }
  src32[e] = s; dst32[e] = d;
  rank[e] = atomicAdd(&counts[d * CSTRIDE], 1);  // old value = within-dst slot
}

// ------- scan stage A: per-chunk sums (strided padded counts) --------------
__global__ __launch_bounds__(256) void scan_a_kernel(
    const int* __restrict__ counts, int* __restrict__ bsum, int N) {
  __shared__ int ws[4];
  int tid = threadIdx.x;
  int i0 = blockIdx.x * SCAN_CHUNK + tid * 8;
  int s = 0;
  #pragma unroll
  for (int j = 0; j < 8; ++j)
    if (i0 + j < N) s += counts[(size_t)(i0 + j) * CSTRIDE];
  #pragma unroll
  for (int m = 32; m; m >>= 1) s += __shfl_xor(s, m);
  int lane = tid & 63, wv = tid >> 6;
  if (lane == 0) ws[wv] = s;
  __syncthreads();
  if (tid == 0) bsum[blockIdx.x] = ws[0] + ws[1] + ws[2] + ws[3];
}

// ------- scan stage C: per-chunk exclusive scan + cross-chunk base ---------
__global__ __launch_bounds__(256) void scan_c_kernel(
    const int* __restrict__ counts, const int* __restrict__ bsum,
    int* __restrict__ offsets, int N, int E) {
  __shared__ int wsum[4];
  int tid = threadIdx.x, lane = tid & 63, wv = tid >> 6;

  int bse = 0;
  for (int j = lane; j < (int)blockIdx.x; j += 64) bse += bsum[j];
  #pragma unroll
  for (int m = 32; m; m >>= 1) bse += __shfl_xor(bse, m);

  int i0 = blockIdx.x * SCAN_CHUNK + tid * 8;
  int v[8];
  #pragma unroll
  for (int j = 0; j < 8; ++j)
    v[j] = (i0 + j < N) ? counts[(size_t)(i0 + j) * CSTRIDE] : 0;
  int pre[8], t = 0;
  #pragma unroll
  for (int j = 0; j < 8; ++j) { pre[j] = t; t += v[j]; }
  int x = t;
  #pragma unroll
  for (int off = 1; off < 64; off <<= 1) {
    int u = __shfl_up(x, off);
    if (lane >= off) x += u;
  }
  if (lane == 63) wsum[wv] = x;
  __syncthreads();
  int waveoff = 0;
  #pragma unroll
  for (int w = 0; w < 4; ++w) if (w < wv) waveoff += wsum[w];
  int ebase = bse + waveoff + (x - t);
  #pragma unroll
  for (int j = 0; j < 8; ++j) {
    int i = i0 + j;
    if (i < N) offsets[i] = ebase + pre[j];
  }
  if (blockIdx.x == 0 && tid == 0) offsets[N] = E;
}

// ------- atomic-free scatter: pos = offsets[dst] + rank --------------------
__global__ __launch_bounds__(256) void scatter_kernel(
    const int* __restrict__ src32, const int* __restrict__ dst32,
    const int* __restrict__ rank, const int* __restrict__ offsets, int E,
    int* __restrict__ csr_src) {
  int e = blockIdx.x * 256 + threadIdx.x;
  if (e >= E) return;
  csr_src[offsets[dst32[e]] + rank[e]] = src32[e];
}

// ---------------- H = X@W + b, fused row L2-norm, fp16 output --------------
// 64-row tile, X staged transposed in LDS (stride 72), 8x4 thread tile,
// f32 accumulate. Templated input dtype (f32 layer1, fp16 layer2).
template <typename TIN>
__global__ __launch_bounds__(256) void gemm_norm_kernel(
    const TIN* __restrict__ X, const float* __restrict__ Wg,
    const float* __restrict__ bias, __half* __restrict__ H16,
    float* __restrict__ rnorm, int N) {
  __shared__ float xt[128][72];  // [k][row], 36.9KB -> 4 blocks/CU
  int tid = threadIdx.x;
  int wv = tid >> 6, lane = tid & 63;
  int rowgrp = lane >> 5;
  int colgrp = lane & 31;
  int rbase = wv * 16 + rowgrp * 8;
  float4 bj = ((const float4*)bias)[colgrp];
  int r0 = blockIdx.x * 64;

  for (int idx = tid; idx < 64 * 128; idx += 256) {
    int rr = idx >> 7, cc = idx & 127;
    int r = r0 + rr; if (r >= N) r = N - 1;
    xt[cc][rr] = (float)X[(size_t)r * 128 + cc];
  }
  __syncthreads();

  float4 a[8];
  #pragma unroll
  for (int rr = 0; rr < 8; ++rr) a[rr] = bj;

  #pragma unroll 4
  for (int k = 0; k < 128; ++k) {
    float4 w = *(const float4*)(Wg + k * 128 + 4 * colgrp);
    float4 xv0 = *(const float4*)&xt[k][rbase];
    float4 xv1 = *(const float4*)&xt[k][rbase + 4];
    a[0].x += xv0.x*w.x; a[0].y += xv0.x*w.y; a[0].z += xv0.x*w.z; a[0].w += xv0.x*w.w;
    a[1].x += xv0.y*w.x; a[1].y += xv0.y*w.y; a[1].z += xv0.y*w.z; a[1].w += xv0.y*w.w;
    a[2].x += xv0.z*w.x; a[2].y += xv0.z*w.y; a[2].z += xv0.z*w.z; a[2].w += xv0.z*w.w;
    a[3].x += xv0.w*w.x; a[3].y += xv0.w*w.y; a[3].z += xv0.w*w.z; a[3].w += xv0.w*w.w;
    a[4].x += xv1.x*w.x; a[4].y += xv1.x*w.y; a[4].z += xv1.x*w.z; a[4].w += xv1.x*w.w;
    a[5].x += xv1.y*w.x; a[5].y += xv1.y*w.y; a[5].z += xv1.y*w.z; a[5].w += xv1.y*w.w;
    a[6].x += xv1.z*w.x; a[6].y += xv1.z*w.y; a[6].z += xv1.z*w.z; a[6].w += xv1.z*w.w;
    a[7].x += xv1.w*w.x; a[7].y += xv1.w*w.y; a[7].z += xv1.w*w.z; a[7].w += xv1.w*w.w;
  }

  #pragma unroll
  for (int rr = 0; rr < 8; ++rr) {
    float4 aa = a[rr];
    float s = aa.x*aa.x + aa.y*aa.y + aa.z*aa.z + aa.w*aa.w;
    #pragma unroll
    for (int m = 16; m; m >>= 1) s += __shfl_xor(s, m);  // 32-lane col group
    int r = r0 + rbase + rr;
    if (r < N) {
      __half2 lo = __floats2half2_rn(aa.x, aa.y);
      __half2 hi = __floats2half2_rn(aa.z, aa.w);
      __half2* dst = (__half2*)(H16 + (size_t)r * 128 + 4 * colgrp);
      dst[0] = lo; dst[1] = hi;
      if (colgrp == 0) rnorm[r] = rsqrtf(s + 1e-12f);
    }
  }
}

// ---------------- fused attention softmax + aggregate + relu ---------------
// One wave per dst node, 4 groups x 16 lanes; each group scores a different
// edge; sublane l holds dims 8l..8l+7 (one 16B fp16 gather per edge).
// Prefetch depth 2: three gather generations in flight per lane.
// score = beta * rnorm[d] * rnorm[s] * (h_d . h_s); |score|<=|beta| so no
// max-subtraction needed (softmax shift-invariant).
template <bool OUT_HALF>
__global__ __launch_bounds__(256) void agg_kernel(
    const __half* __restrict__ H16, const float* __restrict__ rnorm,
    const float* __restrict__ beta_p, const int* __restrict__ offsets,
    const int* __restrict__ csr_src, void* __restrict__ Yp, int N) {
  int wid = (blockIdx.x * 256 + threadIdx.x) >> 6;
  int lane = threadIdx.x & 63;
  if (wid >= N) return;
  int g = lane >> 4;
  int l = lane & 15;
  const float4* H4 = (const float4*)H16;

  float4 hdv = H4[(size_t)wid * 16 + l];
  const __half2* hdp = (const __half2*)&hdv;
  float2 d0 = __half22float2(hdp[0]);
  float2 d1 = __half22float2(hdp[1]);
  float2 d2 = __half22float2(hdp[2]);
  float2 d3 = __half22float2(hdp[3]);
  float rdb = rnorm[wid] * beta_p[0];

  int e0 = offsets[wid], e1 = offsets[wid + 1];
  float denom = 0.f;
  float acc[8] = {0.f,0.f,0.f,0.f,0.f,0.f,0.f,0.f};

  // software pipeline, depth 2 (stages A=current, B=next)
  int eA = e0 + g;
  bool vA = eA < e1;
  int sA = vA ? csr_src[eA] : wid;
  float4 hA = H4[(size_t)sA * 16 + l];
  float rA = rnorm[sA];

  int eB = eA + 4;
  bool vB = eB < e1;
  int sB = vB ? csr_src[eB] : wid;
  float4 hB = H4[(size_t)sB * 16 + l];
  float rB = rnorm[sB];

  for (int eb = e0; eb < e1; eb += 4) {
    // issue generation C loads (edge eb+8+g)
    int eC = eb + 8 + g;
    bool vC = eC < e1;
    int sC = vC ? csr_src[eC] : wid;
    float4 hC = H4[(size_t)sC * 16 + l];
    float rC = rnorm[sC];

    // score + accumulate stage A
    const __half2* hp = (const __half2*)&hA;
    float2 q0 = __half22float2(hp[0]);
    float2 q1 = __half22float2(hp[1]);
    float2 q2 = __half22float2(hp[2]);
    float2 q3 = __half22float2(hp[3]);
    float p = q0.x*d0.x + q0.y*d0.y + q1.x*d1.x + q1.y*d1.y
            + q2.x*d2.x + q2.y*d2.y + q3.x*d3.x + q3.y*d3.y;
    p += __shfl_xor(p, 1);
    p += __shfl_xor(p, 2);
    p += __shfl_xor(p, 4);
    p += __shfl_xor(p, 8);
    float w = vA ? __expf(p * rdb * rA) : 0.f;
    denom += w;
    acc[0] += w*q0.x; acc[1] += w*q0.y; acc[2] += w*q1.x; acc[3] += w*q1.y;
    acc[4] += w*q2.x; acc[5] += w*q2.y; acc[6] += w*q3.x; acc[7] += w*q3.y;

    // rotate: A <- B <- C
    vA = vB; hA = hB; rA = rB;
    vB = vC; hB = hC; rB = rC;
  }

  #pragma unroll
  for (int m = 16; m <= 32; m <<= 1) {
    denom += __shfl_xor(denom, m);
    #pragma unroll
    for (int j = 0; j < 8; ++j) acc[j] += __shfl_xor(acc[j], m);
  }
  if (g == 0) {
    float inv = 1.0f / denom;  // denom > 0 guaranteed by self-loop
    float o[8];
    #pragma unroll
    for (int j = 0; j < 8; ++j) o[j] = fmaxf(acc[j] * inv, 0.f);
    if constexpr (OUT_HALF) {
      float4 pack;
      __half2* hp2 = (__half2*)&pack;
      hp2[0] = __floats2half2_rn(o[0], o[1]);
      hp2[1] = __floats2half2_rn(o[2], o[3]);
      hp2[2] = __floats2half2_rn(o[4], o[5]);
      hp2[3] = __floats2half2_rn(o[6], o[7]);
      ((float4*)Yp)[(size_t)wid * 16 + l] = pack;
    } else {
      float4 o0 = {o[0], o[1], o[2], o[3]};
      float4 o1 = {o[4], o[5], o[6], o[7]};
      ((float4*)Yp)[(size_t)wid * 32 + 2 * l] = o0;
      ((float4*)Yp)[(size_t)wid * 32 + 2 * l + 1] = o1;
    }
  }
}

// ---------------- launcher -------------------------------------------------
extern "C" void kernel_launch(void* const* d_in, const int* in_sizes, int n_in,
                              void* d_out, int out_size, void* d_ws, size_t ws_size,
                              hipStream_t stream) {
  const float* x     = (const float*)d_in[0];
  const void*  ei    = d_in[1];
  const float* W1    = (const float*)d_in[2];
  const float* b1    = (const float*)d_in[3];
  const float* beta1 = (const float*)d_in[4];
  const float* W2    = (const float*)d_in[5];
  const float* b2    = (const float*)d_in[6];
  const float* beta2 = (const float*)d_in[7];

  int N = in_sizes[0] / FDIM;
  int E = in_sizes[1] / 2;

  char* p = (char*)d_ws;
  auto alloc = [&](size_t bytes) {
    char* r = p; p += (bytes + 255) & ~size_t(255); return r;
  };
  int*    counts  = (int*)alloc(sizeof(int) * (size_t)N * CSTRIDE);
  int*    offsets = (int*)alloc(sizeof(int) * (N + 1));
  int*    bsum    = (int*)alloc(sizeof(int) * 256);
  int*    src32   = (int*)alloc(sizeof(int) * E);
  int*    dst32   = (int*)alloc(sizeof(int) * E);
  int*    rank    = (int*)alloc(sizeof(int) * E);
  int*    csr     = (int*)alloc(sizeof(int) * E);
  __half* h16     = (__half*)alloc(sizeof(__half) * (size_t)N * FDIM);
  float*  rn      = (float*)alloc(sizeof(float) * N);
  __half* y1h     = (__half*)alloc(sizeof(__half) * (size_t)N * FDIM);

  hipMemsetAsync(counts, 0, sizeof(int) * (size_t)N * CSTRIDE, stream);

  int cb = (E + 255) / 256;
  int gb = (N + 63) / 64;
  int nb = (N + SCAN_CHUNK - 1) / SCAN_CHUNK;
  int ab = (N + 3) / 4;  // 4 waves (dst nodes) per 256-thread block

  convert_count_kernel<<<cb, 256, 0, stream>>>(ei, E, src32, dst32, rank, counts);
  scan_a_kernel<<<nb, 256, 0, stream>>>(counts, bsum, N);
  scan_c_kernel<<<nb, 256, 0, stream>>>(counts, bsum, offsets, N, E);
  scatter_kernel<<<cb, 256, 0, stream>>>(src32, dst32, rank, offsets, E, csr);

  gemm_norm_kernel<float><<<gb, 256, 0, stream>>>(x, W1, b1, h16, rn, N);
  agg_kernel<true><<<ab, 256, 0, stream>>>(h16, rn, beta1, offsets, csr, y1h, N);
  gemm_norm_kernel<__half><<<gb, 256, 0, stream>>>(y1h, W2, b2, h16, rn, N);
  agg_kernel<false><<<ab, 256, 0, stream>>>(h16, rn, beta2, offsets, csr, d_out, N);
}

// Round 7
// 266.905 us; speedup vs baseline: 1.0341x; 1.0341x over previous
//
#include <hip/hip_runtime.h>
#include <hip/hip_bf16.h>
#include <hip/hip_fp16.h>

// AGNN 2-layer encoder: N=50000 nodes, E=850000 edges (w/ self-loops), D=H=128.
// R7: gemm1+convert re-fused (32-row gemm tile -> 18KB LDS -> 8 blk/CU so
// convert keeps occupancy), convert MLP=8 (tests outstanding-atomic model),
// scatter MLP=4, unpadded counters restored.

#define FDIM 128
#define SCAN_CHUNK 2048   // 256 threads x 8 elems
#define CONV_EPT 8        // edges per thread in convert
#define SCAT_EPT 4        // edges per thread in scatter

// ------- convert body: edges -> int32, histogram + within-dst rank ---------
// dtype detect fused: int64 <=> odd 32-bit words of first 32 entries all 0.
// 8 edges/thread -> 8 independent returning atomics in flight per thread.
__device__ __forceinline__ void convert_body(
    const void* __restrict__ ei, int E,
    int* __restrict__ src32, int* __restrict__ dst32,
    int* __restrict__ rank, int* __restrict__ counts, int cbid) {
  const int* eii = (const int*)ei;
  int lane = threadIdx.x & 63;
  int ok = (lane < 32) ? (eii[2 * lane + 1] == 0) : 1;
  bool is64 = (__ballot(ok) == ~0ull);

  int base = (cbid * 256 + threadIdx.x) * CONV_EPT;
  if (base + CONV_EPT <= E) {
    int s[CONV_EPT], d[CONV_EPT], r[CONV_EPT];
    if (is64) {
      const long long* p = (const long long*)ei;
      #pragma unroll
      for (int j = 0; j < CONV_EPT; ++j) { s[j] = (int)p[base + j]; d[j] = (int)p[E + base + j]; }
    } else {
      #pragma unroll
      for (int j = 0; j < CONV_EPT; ++j) { s[j] = eii[base + j]; d[j] = eii[E + base + j]; }
    }
    #pragma unroll
    for (int j = 0; j < CONV_EPT; ++j) r[j] = atomicAdd(&counts[d[j]], 1);
    #pragma unroll
    for (int j = 0; j < CONV_EPT; ++j) {
      src32[base + j] = s[j]; dst32[base + j] = d[j]; rank[base + j] = r[j];
    }
  } else {
    for (int j = 0; j < CONV_EPT; ++j) {
      int e = base + j; if (e >= E) break;
      int ss, dd;
      if (is64) { const long long* p = (const long long*)ei; ss = (int)p[e]; dd = (int)p[E + e]; }
      else      { ss = eii[e]; dd = eii[E + e]; }
      src32[e] = ss; dst32[e] = dd; rank[e] = atomicAdd(&counts[dd], 1);
    }
  }
}

// ------- gemm 32-row-tile body (18.4KB LDS -> 8 blocks/CU when fused) ------
// Thread tile 4x4: rows wv*8+rowgrp*4..+3, cols 4*colgrp..+3. f32 accum,
// fp16 H out + f32 rnorm.
template <typename TIN>
__device__ __forceinline__ void gemm32_body(
    const TIN* __restrict__ X, const float* __restrict__ Wg,
    const float* __restrict__ bias, __half* __restrict__ H16,
    float* __restrict__ rnorm, int N, int bid) {
  __shared__ float xt[128][36];  // [k][row], 18.4KB
  int tid = threadIdx.x;
  int wv = tid >> 6, lane = tid & 63;
  int rowgrp = lane >> 5;
  int colgrp = lane & 31;
  int rbase = wv * 8 + rowgrp * 4;
  float4 bj = ((const float4*)bias)[colgrp];
  int r0 = bid * 32;

  for (int idx = tid; idx < 32 * 128; idx += 256) {
    int rr = idx >> 7, cc = idx & 127;
    int r = r0 + rr; if (r >= N) r = N - 1;
    xt[cc][rr] = (float)X[(size_t)r * 128 + cc];
  }
  __syncthreads();

  float4 a0 = bj, a1 = bj, a2 = bj, a3 = bj;
  #pragma unroll 8
  for (int k = 0; k < 128; ++k) {
    float4 w = *(const float4*)(Wg + k * 128 + 4 * colgrp);
    float4 xv = *(const float4*)&xt[k][rbase];
    a0.x += xv.x*w.x; a0.y += xv.x*w.y; a0.z += xv.x*w.z; a0.w += xv.x*w.w;
    a1.x += xv.y*w.x; a1.y += xv.y*w.y; a1.z += xv.y*w.z; a1.w += xv.y*w.w;
    a2.x += xv.z*w.x; a2.y += xv.z*w.y; a2.z += xv.z*w.z; a2.w += xv.z*w.w;
    a3.x += xv.w*w.x; a3.y += xv.w*w.y; a3.z += xv.w*w.z; a3.w += xv.w*w.w;
  }

  float4 av[4] = {a0, a1, a2, a3};
  #pragma unroll
  for (int rr = 0; rr < 4; ++rr) {
    float4 aa = av[rr];
    float s = aa.x*aa.x + aa.y*aa.y + aa.z*aa.z + aa.w*aa.w;
    #pragma unroll
    for (int m = 16; m; m >>= 1) s += __shfl_xor(s, m);  // 32-lane col group
    int r = r0 + rbase + rr;
    if (r < N) {
      __half2 lo = __floats2half2_rn(aa.x, aa.y);
      __half2 hi = __floats2half2_rn(aa.z, aa.w);
      __half2* dst = (__half2*)(H16 + (size_t)r * 128 + 4 * colgrp);
      dst[0] = lo; dst[1] = hi;
      if (colgrp == 0) rnorm[r] = rsqrtf(s + 1e-12f);
    }
  }
}

// ------- fused dispatch: gemm1 blocks [0,GB) + convert blocks [GB,GB+CB) ---
__global__ __launch_bounds__(256) void gemm1_convert_kernel(
    const float* __restrict__ X, const float* __restrict__ Wg,
    const float* __restrict__ bias, __half* __restrict__ H16,
    float* __restrict__ rnorm, int N, int GB,
    const void* __restrict__ ei, int E,
    int* __restrict__ src32, int* __restrict__ dst32,
    int* __restrict__ rank, int* __restrict__ counts) {
  if ((int)blockIdx.x < GB)
    gemm32_body<float>(X, Wg, bias, H16, rnorm, N, blockIdx.x);
  else
    convert_body(ei, E, src32, dst32, rank, counts, blockIdx.x - GB);
}

// ------- scan stage A: per-chunk sums --------------------------------------
__global__ __launch_bounds__(256) void scan_a_kernel(
    const int* __restrict__ counts, int* __restrict__ bsum, int N) {
  __shared__ int ws[4];
  int tid = threadIdx.x;
  int i0 = blockIdx.x * SCAN_CHUNK + tid * 8;
  int s = 0;
  if (i0 + 7 < N) {
    int4 a = *(const int4*)(counts + i0);
    int4 b = *(const int4*)(counts + i0 + 4);
    s = a.x + a.y + a.z + a.w + b.x + b.y + b.z + b.w;
  } else {
    #pragma unroll
    for (int j = 0; j < 8; ++j) if (i0 + j < N) s += counts[i0 + j];
  }
  #pragma unroll
  for (int m = 32; m; m >>= 1) s += __shfl_xor(s, m);
  int lane = tid & 63, wv = tid >> 6;
  if (lane == 0) ws[wv] = s;
  __syncthreads();
  if (tid == 0) bsum[blockIdx.x] = ws[0] + ws[1] + ws[2] + ws[3];
}

// ------- scan stage C: per-chunk exclusive scan + cross-chunk base ---------
__global__ __launch_bounds__(256) void scan_c_kernel(
    const int* __restrict__ counts, const int* __restrict__ bsum,
    int* __restrict__ offsets, int N, int E) {
  __shared__ int wsum[4];
  int tid = threadIdx.x, lane = tid & 63, wv = tid >> 6;

  int bse = 0;
  for (int j = lane; j < (int)blockIdx.x; j += 64) bse += bsum[j];
  #pragma unroll
  for (int m = 32; m; m >>= 1) bse += __shfl_xor(bse, m);

  int i0 = blockIdx.x * SCAN_CHUNK + tid * 8;
  int v[8];
  if (i0 + 7 < N) {
    int4 a = *(const int4*)(counts + i0);
    int4 b = *(const int4*)(counts + i0 + 4);
    v[0]=a.x; v[1]=a.y; v[2]=a.z; v[3]=a.w;
    v[4]=b.x; v[5]=b.y; v[6]=b.z; v[7]=b.w;
  } else {
    #pragma unroll
    for (int j = 0; j < 8; ++j) v[j] = (i0 + j < N) ? counts[i0 + j] : 0;
  }
  int pre[8], t = 0;
  #pragma unroll
  for (int j = 0; j < 8; ++j) { pre[j] = t; t += v[j]; }
  int x = t;
  #pragma unroll
  for (int off = 1; off < 64; off <<= 1) {
    int u = __shfl_up(x, off);
    if (lane >= off) x += u;
  }
  if (lane == 63) wsum[wv] = x;
  __syncthreads();
  int waveoff = 0;
  #pragma unroll
  for (int w = 0; w < 4; ++w) if (w < wv) waveoff += wsum[w];
  int ebase = bse + waveoff + (x - t);
  #pragma unroll
  for (int j = 0; j < 8; ++j) {
    int i = i0 + j;
    if (i < N) offsets[i] = ebase + pre[j];
  }
  if (blockIdx.x == 0 && tid == 0) offsets[N] = E;
}

// ------- atomic-free scatter, 4 edges/thread (4 stores in flight) ----------
__global__ __launch_bounds__(256) void scatter_kernel(
    const int* __restrict__ src32, const int* __restrict__ dst32,
    const int* __restrict__ rank, const int* __restrict__ offsets, int E,
    int* __restrict__ csr_src) {
  int base = (blockIdx.x * 256 + threadIdx.x) * SCAT_EPT;
  if (base + SCAT_EPT <= E) {
    int4 s = *(const int4*)(src32 + base);
    int4 d = *(const int4*)(dst32 + base);
    int4 r = *(const int4*)(rank + base);
    int o0 = offsets[d.x], o1 = offsets[d.y], o2 = offsets[d.z], o3 = offsets[d.w];
    csr_src[o0 + r.x] = s.x;
    csr_src[o1 + r.y] = s.y;
    csr_src[o2 + r.z] = s.z;
    csr_src[o3 + r.w] = s.w;
  } else {
    for (int j = 0; j < SCAT_EPT; ++j) {
      int e = base + j; if (e >= E) break;
      csr_src[offsets[dst32[e]] + rank[e]] = src32[e];
    }
  }
}

// ---------------- H = X@W + b standalone (64-row tile, layer 2) ------------
template <typename TIN>
__global__ __launch_bounds__(256) void gemm_norm_kernel(
    const TIN* __restrict__ X, const float* __restrict__ Wg,
    const float* __restrict__ bias, __half* __restrict__ H16,
    float* __restrict__ rnorm, int N) {
  __shared__ float xt[128][72];  // [k][row], 36.9KB
  int tid = threadIdx.x;
  int wv = tid >> 6, lane = tid & 63;
  int rowgrp = lane >> 5;
  int colgrp = lane & 31;
  int rbase = wv * 16 + rowgrp * 8;
  float4 bj = ((const float4*)bias)[colgrp];
  int r0 = blockIdx.x * 64;

  for (int idx = tid; idx < 64 * 128; idx += 256) {
    int rr = idx >> 7, cc = idx & 127;
    int r = r0 + rr; if (r >= N) r = N - 1;
    xt[cc][rr] = (float)X[(size_t)r * 128 + cc];
  }
  __syncthreads();

  float4 a[8];
  #pragma unroll
  for (int rr = 0; rr < 8; ++rr) a[rr] = bj;

  #pragma unroll 4
  for (int k = 0; k < 128; ++k) {
    float4 w = *(const float4*)(Wg + k * 128 + 4 * colgrp);
    float4 xv0 = *(const float4*)&xt[k][rbase];
    float4 xv1 = *(const float4*)&xt[k][rbase + 4];
    a[0].x += xv0.x*w.x; a[0].y += xv0.x*w.y; a[0].z += xv0.x*w.z; a[0].w += xv0.x*w.w;
    a[1].x += xv0.y*w.x; a[1].y += xv0.y*w.y; a[1].z += xv0.y*w.z; a[1].w += xv0.y*w.w;
    a[2].x += xv0.z*w.x; a[2].y += xv0.z*w.y; a[2].z += xv0.z*w.z; a[2].w += xv0.z*w.w;
    a[3].x += xv0.w*w.x; a[3].y += xv0.w*w.y; a[3].z += xv0.w*w.z; a[3].w += xv0.w*w.w;
    a[4].x += xv1.x*w.x; a[4].y += xv1.x*w.y; a[4].z += xv1.x*w.z; a[4].w += xv1.x*w.w;
    a[5].x += xv1.y*w.x; a[5].y += xv1.y*w.y; a[5].z += xv1.y*w.z; a[5].w += xv1.y*w.w;
    a[6].x += xv1.z*w.x; a[6].y += xv1.z*w.y; a[6].z += xv1.z*w.z; a[6].w += xv1.z*w.w;
    a[7].x += xv1.w*w.x; a[7].y += xv1.w*w.y; a[7].z += xv1.w*w.z; a[7].w += xv1.w*w.w;
  }

  #pragma unroll
  for (int rr = 0; rr < 8; ++rr) {
    float4 aa = a[rr];
    float s = aa.x*aa.x + aa.y*aa.y + aa.z*aa.z + aa.w*aa.w;
    #pragma unroll
    for (int m = 16; m; m >>= 1) s += __shfl_xor(s, m);  // 32-lane col group
    int r = r0 + rbase + rr;
    if (r < N) {
      __half2 lo = __floats2half2_rn(aa.x, aa.y);
      __half2 hi = __floats2half2_rn(aa.z, aa.w);
      __half2* dst = (__half2*)(H16 + (size_t)r * 128 + 4 * colgrp);
      dst[0] = lo; dst[1] = hi;
      if (colgrp == 0) rnorm[r] = rsqrtf(s + 1e-12f);
    }
  }
}

// ---------------- fused attention softmax + aggregate + relu ---------------
// One wave per dst node, 4 groups x 16 lanes; each group scores a different
// edge; sublane l holds dims 8l..8l+7 (one 16B fp16 gather per edge).
// Prefetch depth 2: three gather generations in flight per lane.
template <bool OUT_HALF>
__global__ __launch_bounds__(256) void agg_kernel(
    const __half* __restrict__ H16, const float* __restrict__ rnorm,
    const float* __restrict__ beta_p, const int* __restrict__ offsets,
    const int* __restrict__ csr_src, void* __restrict__ Yp, int N) {
  int wid = (blockIdx.x * 256 + threadIdx.x) >> 6;
  int lane = threadIdx.x & 63;
  if (wid >= N) return;
  int g = lane >> 4;
  int l = lane & 15;
  const float4* H4 = (const float4*)H16;

  float4 hdv = H4[(size_t)wid * 16 + l];
  const __half2* hdp = (const __half2*)&hdv;
  float2 d0 = __half22float2(hdp[0]);
  float2 d1 = __half22float2(hdp[1]);
  float2 d2 = __half22float2(hdp[2]);
  float2 d3 = __half22float2(hdp[3]);
  float rdb = rnorm[wid] * beta_p[0];

  int e0 = offsets[wid], e1 = offsets[wid + 1];
  float denom = 0.f;
  float acc[8] = {0.f,0.f,0.f,0.f,0.f,0.f,0.f,0.f};

  int eA = e0 + g;
  bool vA = eA < e1;
  int sA = vA ? csr_src[eA] : wid;
  float4 hA = H4[(size_t)sA * 16 + l];
  float rA = rnorm[sA];

  int eB = eA + 4;
  bool vB = eB < e1;
  int sB = vB ? csr_src[eB] : wid;
  float4 hB = H4[(size_t)sB * 16 + l];
  float rB = rnorm[sB];

  for (int eb = e0; eb < e1; eb += 4) {
    int eC = eb + 8 + g;
    bool vC = eC < e1;
    int sC = vC ? csr_src[eC] : wid;
    float4 hC = H4[(size_t)sC * 16 + l];
    float rC = rnorm[sC];

    const __half2* hp = (const __half2*)&hA;
    float2 q0 = __half22float2(hp[0]);
    float2 q1 = __half22float2(hp[1]);
    float2 q2 = __half22float2(hp[2]);
    float2 q3 = __half22float2(hp[3]);
    float p = q0.x*d0.x + q0.y*d0.y + q1.x*d1.x + q1.y*d1.y
            + q2.x*d2.x + q2.y*d2.y + q3.x*d3.x + q3.y*d3.y;
    p += __shfl_xor(p, 1);
    p += __shfl_xor(p, 2);
    p += __shfl_xor(p, 4);
    p += __shfl_xor(p, 8);
    float w = vA ? __expf(p * rdb * rA) : 0.f;
    denom += w;
    acc[0] += w*q0.x; acc[1] += w*q0.y; acc[2] += w*q1.x; acc[3] += w*q1.y;
    acc[4] += w*q2.x; acc[5] += w*q2.y; acc[6] += w*q3.x; acc[7] += w*q3.y;

    vA = vB; hA = hB; rA = rB;
    vB = vC; hB = hC; rB = rC;
  }

  #pragma unroll
  for (int m = 16; m <= 32; m <<= 1) {
    denom += __shfl_xor(denom, m);
    #pragma unroll
    for (int j = 0; j < 8; ++j) acc[j] += __shfl_xor(acc[j], m);
  }
  if (g == 0) {
    float inv = 1.0f / denom;  // denom > 0 guaranteed by self-loop
    float o[8];
    #pragma unroll
    for (int j = 0; j < 8; ++j) o[j] = fmaxf(acc[j] * inv, 0.f);
    if constexpr (OUT_HALF) {
      float4 pack;
      __half2* hp2 = (__half2*)&pack;
      hp2[0] = __floats2half2_rn(o[0], o[1]);
      hp2[1] = __floats2half2_rn(o[2], o[3]);
      hp2[2] = __floats2half2_rn(o[4], o[5]);
      hp2[3] = __floats2half2_rn(o[6], o[7]);
      ((float4*)Yp)[(size_t)wid * 16 + l] = pack;
    } else {
      float4 o0 = {o[0], o[1], o[2], o[3]};
      float4 o1 = {o[4], o[5], o[6], o[7]};
      ((float4*)Yp)[(size_t)wid * 32 + 2 * l] = o0;
      ((float4*)Yp)[(size_t)wid * 32 + 2 * l + 1] = o1;
    }
  }
}

// ---------------- launcher -------------------------------------------------
extern "C" void kernel_launch(void* const* d_in, const int* in_sizes, int n_in,
                              void* d_out, int out_size, void* d_ws, size_t ws_size,
                              hipStream_t stream) {
  const float* x     = (const float*)d_in[0];
  const void*  ei    = d_in[1];
  const float* W1    = (const float*)d_in[2];
  const float* b1    = (const float*)d_in[3];
  const float* beta1 = (const float*)d_in[4];
  const float* W2    = (const float*)d_in[5];
  const float* b2    = (const float*)d_in[6];
  const float* beta2 = (const float*)d_in[7];

  int N = in_sizes[0] / FDIM;
  int E = in_sizes[1] / 2;

  char* p = (char*)d_ws;
  auto alloc = [&](size_t bytes) {
    char* r = p; p += (bytes + 255) & ~size_t(255); return r;
  };
  int*    counts  = (int*)alloc(sizeof(int) * N);
  int*    offsets = (int*)alloc(sizeof(int) * (N + 1));
  int*    bsum    = (int*)alloc(sizeof(int) * 256);
  int*    src32   = (int*)alloc(sizeof(int) * E);
  int*    dst32   = (int*)alloc(sizeof(int) * E);
  int*    rank    = (int*)alloc(sizeof(int) * E);
  int*    csr     = (int*)alloc(sizeof(int) * E);
  __half* h16     = (__half*)alloc(sizeof(__half) * (size_t)N * FDIM);
  float*  rn      = (float*)alloc(sizeof(float) * N);
  __half* y1h     = (__half*)alloc(sizeof(__half) * (size_t)N * FDIM);

  hipMemsetAsync(counts, 0, sizeof(int) * N, stream);

  int gb1 = (N + 31) / 32;                         // 32-row gemm tiles
  int cb  = (E + 256 * CONV_EPT - 1) / (256 * CONV_EPT);
  int sb  = (E + 256 * SCAT_EPT - 1) / (256 * SCAT_EPT);
  int nb  = (N + SCAN_CHUNK - 1) / SCAN_CHUNK;
  int gb2 = (N + 63) / 64;                         // 64-row gemm tiles
  int ab  = (N + 3) / 4;  // 4 waves (dst nodes) per 256-thread block

  // gemm1 (VALU/LDS) overlapped with convert (atomic latency), 8 blk/CU LDS
  gemm1_convert_kernel<<<gb1 + cb, 256, 0, stream>>>(
      x, W1, b1, h16, rn, N, gb1, ei, E, src32, dst32, rank, counts);
  scan_a_kernel<<<nb, 256, 0, stream>>>(counts, bsum, N);
  scan_c_kernel<<<nb, 256, 0, stream>>>(counts, bsum, offsets, N, E);
  scatter_kernel<<<sb, 256, 0, stream>>>(src32, dst32, rank, offsets, E, csr);

  agg_kernel<true><<<ab, 256, 0, stream>>>(h16, rn, beta1, offsets, csr, y1h, N);
  gemm_norm_kernel<__half><<<gb2, 256, 0, stream>>>(y1h, W2, b2, h16, rn, N);
  agg_kernel<false><<<ab, 256, 0, stream>>>(h16, rn, beta2, offsets, csr, d_out, N);
}

// Round 8
// 239.093 us; speedup vs baseline: 1.1544x; 1.1163x over previous
//
#include <hip/hip_runtime.h>
#include <hip/hip_bf16.h>
#include <hip/hip_fp16.h>

// AGNN 2-layer encoder: N=50000 nodes, E=850000 edges (w/ self-loops), D=H=128.
// R8: MFMA fp16 GEMM (pre-packed W frags, 17.4KB LDS) fused with convert
// (convert blocks first, full occupancy); fdot2 in agg. Atomic histogram is a
// device-wide-throughput wall (~43us for 850K returning atomics) -> hide it.

#define FDIM 128
#define SCAN_CHUNK 2048   // 256 threads x 8 elems
#define SCAT_EPT 4        // edges per thread in scatter

typedef _Float16 f16x8 __attribute__((ext_vector_type(8)));
typedef _Float16 f16x2 __attribute__((ext_vector_type(2)));
typedef float f32x4 __attribute__((ext_vector_type(4)));

#if defined(__has_builtin)
#if __has_builtin(__builtin_amdgcn_fdot2)
#define HAS_FDOT2 1
#endif
#endif

// ------- pack W (f32 [K=128][N=128]) into fp16 B-fragment layout -----------
// B frag for mfma_f32_16x16x32_f16: lane l holds B[k=kt*32+(l>>4)*8+j][col=nt*16+(l&15)].
// Linear: wp[((nt*4+kt)*64 + l)*8 + j]. One kernel packs both W1 and W2.
__global__ __launch_bounds__(256) void pack_w_kernel(
    const float* __restrict__ W1, const float* __restrict__ W2,
    _Float16* __restrict__ wp1, _Float16* __restrict__ wp2) {
  int t = blockIdx.x * 256 + threadIdx.x;            // 0..4095
  const float* W = (t < 2048) ? W1 : W2;
  _Float16* wp   = (t < 2048) ? wp1 : wp2;
  int tt = t & 2047;
  int l = tt & 63, tile = tt >> 6, kt = tile & 3, nt = tile >> 2;
  int kbase = kt * 32 + (l >> 4) * 8, col = nt * 16 + (l & 15);
  f16x8 v;
  #pragma unroll
  for (int j = 0; j < 8; ++j) v[j] = (_Float16)W[(kbase + j) * 128 + col];
  *(f16x8*)(wp + (size_t)tt * 8) = v;
}

// ------- MFMA gemm body: H = X@W + b, fused row L2-norm, fp16 H out --------
// 64 rows/block, 4 waves (16 rows each). X staged fp16 in LDS [64][136]
// (272B row stride: 16B-aligned ds_read_b128, <=8-way bank alias).
// Per wave: 4 ktiles x (1 ds_read A-frag + 8 x (B-frag load + MFMA)).
// C layout (m89): col=lane&15, row=(lane>>4)*4+reg.
template <typename TIN>
__device__ __forceinline__ void mfma_gemm_body(
    const TIN* __restrict__ X, const _Float16* __restrict__ wp,
    const float* __restrict__ bias, __half* __restrict__ H16,
    float* __restrict__ rnorm, int N, int bid) {
  __shared__ _Float16 xt[64][136];
  int tid = threadIdx.x;
  int l = tid & 63, wv = tid >> 6;
  int r0 = bid * 64;

  for (int idx = tid; idx < 64 * 16; idx += 256) {
    int row = idx >> 4, c8 = idx & 15;
    int r = r0 + row; if (r >= N) r = N - 1;
    f16x8 v;
    if constexpr (sizeof(TIN) == 4) {
      const float* px = (const float*)X + (size_t)r * 128 + c8 * 8;
      float4 a = *(const float4*)px;
      float4 b = *(const float4*)(px + 4);
      v[0]=(_Float16)a.x; v[1]=(_Float16)a.y; v[2]=(_Float16)a.z; v[3]=(_Float16)a.w;
      v[4]=(_Float16)b.x; v[5]=(_Float16)b.y; v[6]=(_Float16)b.z; v[7]=(_Float16)b.w;
    } else {
      v = *(const f16x8*)((const __half*)X + (size_t)r * 128 + c8 * 8);
    }
    *(f16x8*)&xt[row][c8 * 8] = v;
  }
  __syncthreads();

  f32x4 acc[8];
  #pragma unroll
  for (int nt = 0; nt < 8; ++nt) acc[nt] = (f32x4){0.f, 0.f, 0.f, 0.f};

  int arow = wv * 16 + (l & 15);
  int koff = (l >> 4) * 8;
  #pragma unroll
  for (int kt = 0; kt < 4; ++kt) {
    f16x8 afrag = *(const f16x8*)&xt[arow][kt * 32 + koff];
    #pragma unroll
    for (int nt = 0; nt < 8; ++nt) {
      f16x8 bfrag = *(const f16x8*)(wp + (size_t)((nt * 4 + kt) * 64 + l) * 8);
      acc[nt] = __builtin_amdgcn_mfma_f32_16x16x32_f16(afrag, bfrag, acc[nt], 0, 0, 0);
    }
  }

  int col = l & 15, g = l >> 4;
  float bv[8];
  #pragma unroll
  for (int nt = 0; nt < 8; ++nt) bv[nt] = bias[nt * 16 + col];

  #pragma unroll
  for (int j = 0; j < 4; ++j) {
    float hv[8]; float s = 0.f;
    #pragma unroll
    for (int nt = 0; nt < 8; ++nt) { hv[nt] = acc[nt][j] + bv[nt]; s += hv[nt] * hv[nt]; }
    s += __shfl_xor(s, 1); s += __shfl_xor(s, 2);
    s += __shfl_xor(s, 4); s += __shfl_xor(s, 8);   // 16-lane col group (uniform r)
    int r = r0 + wv * 16 + g * 4 + j;
    if (r < N) {
      #pragma unroll
      for (int nt = 0; nt < 8; ++nt)
        H16[(size_t)r * 128 + nt * 16 + col] = __float2half(hv[nt]);
      if (col == 0) rnorm[r] = rsqrtf(s + 1e-12f);
    }
  }
}

// ------- convert body: edges -> int32, histogram + within-dst rank ---------
// dtype detect fused: int64 <=> odd 32-bit words of first 32 entries all 0.
__device__ __forceinline__ void convert_body(
    const void* __restrict__ ei, int E,
    int* __restrict__ src32, int* __restrict__ dst32,
    int* __restrict__ rank, int* __restrict__ counts, int cbid) {
  const int* eii = (const int*)ei;
  int lane = threadIdx.x & 63;
  int ok = (lane < 32) ? (eii[2 * lane + 1] == 0) : 1;
  bool is64 = (__ballot(ok) == ~0ull);

  int base = (cbid * 256 + threadIdx.x) * 2;
  if (base + 2 <= E) {
    int s0, s1, d0, d1;
    if (is64) {
      const long long* p = (const long long*)ei;
      longlong2 sv = *(const longlong2*)(p + base);
      longlong2 dv = *(const longlong2*)(p + E + base);
      s0 = (int)sv.x; s1 = (int)sv.y; d0 = (int)dv.x; d1 = (int)dv.y;
    } else {
      int2 sv = *(const int2*)(eii + base);
      int2 dv = *(const int2*)(eii + E + base);
      s0 = sv.x; s1 = sv.y; d0 = dv.x; d1 = dv.y;
    }
    int r0 = atomicAdd(&counts[d0], 1);
    int r1 = atomicAdd(&counts[d1], 1);
    *(int2*)(src32 + base) = make_int2(s0, s1);
    *(int2*)(dst32 + base) = make_int2(d0, d1);
    *(int2*)(rank + base)  = make_int2(r0, r1);
  } else {
    for (int e = base; e < E; ++e) {
      int ss, dd;
      if (is64) { const long long* p = (const long long*)ei; ss = (int)p[e]; dd = (int)p[E + e]; }
      else      { ss = eii[e]; dd = eii[E + e]; }
      src32[e] = ss; dst32[e] = dd; rank[e] = atomicAdd(&counts[dd], 1);
    }
  }
}

// ------- fused dispatch: convert blocks [0,CB) FIRST, then gemm1 -----------
// Convert (43us atomic-latency wall, needs occupancy) saturates the device
// from t=0; gemm1 MFMA blocks (~10us total) hide underneath. 17.4KB LDS ->
// 8 blocks/CU -> 32 waves/CU even for convert blocks.
__global__ __launch_bounds__(256) void convert_gemm1_kernel(
    const void* __restrict__ ei, int E,
    int* __restrict__ src32, int* __restrict__ dst32,
    int* __restrict__ rank, int* __restrict__ counts, int CB,
    const float* __restrict__ X, const _Float16* __restrict__ wp1,
    const float* __restrict__ bias, __half* __restrict__ H16,
    float* __restrict__ rnorm, int N) {
  if ((int)blockIdx.x < CB)
    convert_body(ei, E, src32, dst32, rank, counts, blockIdx.x);
  else
    mfma_gemm_body<float>(X, wp1, bias, H16, rnorm, N, blockIdx.x - CB);
}

// ------- standalone MFMA gemm (layer 2, fp16 input) ------------------------
__global__ __launch_bounds__(256) void gemm2_kernel(
    const __half* __restrict__ X, const _Float16* __restrict__ wp,
    const float* __restrict__ bias, __half* __restrict__ H16,
    float* __restrict__ rnorm, int N) {
  mfma_gemm_body<__half>(X, wp, bias, H16, rnorm, N, blockIdx.x);
}

// ------- scan stage A: per-chunk sums --------------------------------------
__global__ __launch_bounds__(256) void scan_a_kernel(
    const int* __restrict__ counts, int* __restrict__ bsum, int N) {
  __shared__ int ws[4];
  int tid = threadIdx.x;
  int i0 = blockIdx.x * SCAN_CHUNK + tid * 8;
  int s = 0;
  if (i0 + 7 < N) {
    int4 a = *(const int4*)(counts + i0);
    int4 b = *(const int4*)(counts + i0 + 4);
    s = a.x + a.y + a.z + a.w + b.x + b.y + b.z + b.w;
  } else {
    #pragma unroll
    for (int j = 0; j < 8; ++j) if (i0 + j < N) s += counts[i0 + j];
  }
  #pragma unroll
  for (int m = 32; m; m >>= 1) s += __shfl_xor(s, m);
  int lane = tid & 63, wv = tid >> 6;
  if (lane == 0) ws[wv] = s;
  __syncthreads();
  if (tid == 0) bsum[blockIdx.x] = ws[0] + ws[1] + ws[2] + ws[3];
}

// ------- scan stage C: per-chunk exclusive scan + cross-chunk base ---------
__global__ __launch_bounds__(256) void scan_c_kernel(
    const int* __restrict__ counts, const int* __restrict__ bsum,
    int* __restrict__ offsets, int N, int E) {
  __shared__ int wsum[4];
  int tid = threadIdx.x, lane = tid & 63, wv = tid >> 6;

  int bse = 0;
  for (int j = lane; j < (int)blockIdx.x; j += 64) bse += bsum[j];
  #pragma unroll
  for (int m = 32; m; m >>= 1) bse += __shfl_xor(bse, m);

  int i0 = blockIdx.x * SCAN_CHUNK + tid * 8;
  int v[8];
  if (i0 + 7 < N) {
    int4 a = *(const int4*)(counts + i0);
    int4 b = *(const int4*)(counts + i0 + 4);
    v[0]=a.x; v[1]=a.y; v[2]=a.z; v[3]=a.w;
    v[4]=b.x; v[5]=b.y; v[6]=b.z; v[7]=b.w;
  } else {
    #pragma unroll
    for (int j = 0; j < 8; ++j) v[j] = (i0 + j < N) ? counts[i0 + j] : 0;
  }
  int pre[8], t = 0;
  #pragma unroll
  for (int j = 0; j < 8; ++j) { pre[j] = t; t += v[j]; }
  int x = t;
  #pragma unroll
  for (int off = 1; off < 64; off <<= 1) {
    int u = __shfl_up(x, off);
    if (lane >= off) x += u;
  }
  if (lane == 63) wsum[wv] = x;
  __syncthreads();
  int waveoff = 0;
  #pragma unroll
  for (int w = 0; w < 4; ++w) if (w < wv) waveoff += wsum[w];
  int ebase = bse + waveoff + (x - t);
  #pragma unroll
  for (int j = 0; j < 8; ++j) {
    int i = i0 + j;
    if (i < N) offsets[i] = ebase + pre[j];
  }
  if (blockIdx.x == 0 && tid == 0) offsets[N] = E;
}

// ------- atomic-free scatter, 4 edges/thread -------------------------------
__global__ __launch_bounds__(256) void scatter_kernel(
    const int* __restrict__ src32, const int* __restrict__ dst32,
    const int* __restrict__ rank, const int* __restrict__ offsets, int E,
    int* __restrict__ csr_src) {
  int base = (blockIdx.x * 256 + threadIdx.x) * SCAT_EPT;
  if (base + SCAT_EPT <= E) {
    int4 s = *(const int4*)(src32 + base);
    int4 d = *(const int4*)(dst32 + base);
    int4 r = *(const int4*)(rank + base);
    int o0 = offsets[d.x], o1 = offsets[d.y], o2 = offsets[d.z], o3 = offsets[d.w];
    csr_src[o0 + r.x] = s.x;
    csr_src[o1 + r.y] = s.y;
    csr_src[o2 + r.z] = s.z;
    csr_src[o3 + r.w] = s.w;
  } else {
    for (int j = 0; j < SCAT_EPT; ++j) {
      int e = base + j; if (e >= E) break;
      csr_src[offsets[dst32[e]] + rank[e]] = src32[e];
    }
  }
}

// ---------------- fused attention softmax + aggregate + relu ---------------
// One wave per dst node, 4 groups x 16 lanes; each group scores a different
// edge; sublane l holds dims 8l..8l+7 (one 16B fp16 gather per edge).
// Prefetch depth 2. Dot via v_dot2_f32_f16 (f32 accum) when available.
template <bool OUT_HALF>
__global__ __launch_bounds__(256) void agg_kernel(
    const __half* __restrict__ H16, const float* __restrict__ rnorm,
    const float* __restrict__ beta_p, const int* __restrict__ offsets,
    const int* __restrict__ csr_src, void* __restrict__ Yp, int N) {
  int wid = (blockIdx.x * 256 + threadIdx.x) >> 6;
  int lane = threadIdx.x & 63;
  if (wid >= N) return;
  int g = lane >> 4;
  int l = lane & 15;
  const float4* H4 = (const float4*)H16;

  float4 hdv = H4[(size_t)wid * 16 + l];
  const __half2* hdp = (const __half2*)&hdv;
  float2 d0 = __half22float2(hdp[0]);
  float2 d1 = __half22float2(hdp[1]);
  float2 d2 = __half22float2(hdp[2]);
  float2 d3 = __half22float2(hdp[3]);
  float rdb = rnorm[wid] * beta_p[0];

  int e0 = offsets[wid], e1 = offsets[wid + 1];
  float denom = 0.f;
  float acc[8] = {0.f,0.f,0.f,0.f,0.f,0.f,0.f,0.f};

  int eA = e0 + g;
  bool vA = eA < e1;
  int sA = vA ? csr_src[eA] : wid;
  float4 hA = H4[(size_t)sA * 16 + l];
  float rA = rnorm[sA];

  int eB = eA + 4;
  bool vB = eB < e1;
  int sB = vB ? csr_src[eB] : wid;
  float4 hB = H4[(size_t)sB * 16 + l];
  float rB = rnorm[sB];

  for (int eb = e0; eb < e1; eb += 4) {
    int eC = eb + 8 + g;
    bool vC = eC < e1;
    int sC = vC ? csr_src[eC] : wid;
    float4 hC = H4[(size_t)sC * 16 + l];
    float rC = rnorm[sC];

    const __half2* hp = (const __half2*)&hA;
    float2 q0 = __half22float2(hp[0]);
    float2 q1 = __half22float2(hp[1]);
    float2 q2 = __half22float2(hp[2]);
    float2 q3 = __half22float2(hp[3]);
#ifdef HAS_FDOT2
    const f16x2* ha2 = (const f16x2*)&hA;
    const f16x2* hd2 = (const f16x2*)&hdv;
    float p = 0.f;
    #pragma unroll
    for (int t = 0; t < 4; ++t) p = __builtin_amdgcn_fdot2(ha2[t], hd2[t], p, false);
#else
    float p = q0.x*d0.x + q0.y*d0.y + q1.x*d1.x + q1.y*d1.y
            + q2.x*d2.x + q2.y*d2.y + q3.x*d3.x + q3.y*d3.y;
#endif
    p += __shfl_xor(p, 1);
    p += __shfl_xor(p, 2);
    p += __shfl_xor(p, 4);
    p += __shfl_xor(p, 8);
    float w = vA ? __expf(p * rdb * rA) : 0.f;
    denom += w;
    acc[0] += w*q0.x; acc[1] += w*q0.y; acc[2] += w*q1.x; acc[3] += w*q1.y;
    acc[4] += w*q2.x; acc[5] += w*q2.y; acc[6] += w*q3.x; acc[7] += w*q3.y;

    vA = vB; hA = hB; rA = rB;
    vB = vC; hB = hC; rB = rC;
  }

  #pragma unroll
  for (int m = 16; m <= 32; m <<= 1) {
    denom += __shfl_xor(denom, m);
    #pragma unroll
    for (int j = 0; j < 8; ++j) acc[j] += __shfl_xor(acc[j], m);
  }
  if (g == 0) {
    float inv = 1.0f / denom;  // denom > 0 guaranteed by self-loop
    float o[8];
    #pragma unroll
    for (int j = 0; j < 8; ++j) o[j] = fmaxf(acc[j] * inv, 0.f);
    if constexpr (OUT_HALF) {
      float4 pack;
      __half2* hp2 = (__half2*)&pack;
      hp2[0] = __floats2half2_rn(o[0], o[1]);
      hp2[1] = __floats2half2_rn(o[2], o[3]);
      hp2[2] = __floats2half2_rn(o[4], o[5]);
      hp2[3] = __floats2half2_rn(o[6], o[7]);
      ((float4*)Yp)[(size_t)wid * 16 + l] = pack;
    } else {
      float4 o0 = {o[0], o[1], o[2], o[3]};
      float4 o1 = {o[4], o[5], o[6], o[7]};
      ((float4*)Yp)[(size_t)wid * 32 + 2 * l] = o0;
      ((float4*)Yp)[(size_t)wid * 32 + 2 * l + 1] = o1;
    }
  }
}

// ---------------- launcher -------------------------------------------------
extern "C" void kernel_launch(void* const* d_in, const int* in_sizes, int n_in,
                              void* d_out, int out_size, void* d_ws, size_t ws_size,
                              hipStream_t stream) {
  const float* x     = (const float*)d_in[0];
  const void*  ei    = d_in[1];
  const float* W1    = (const float*)d_in[2];
  const float* b1    = (const float*)d_in[3];
  const float* beta1 = (const float*)d_in[4];
  const float* W2    = (const float*)d_in[5];
  const float* b2    = (const float*)d_in[6];
  const float* beta2 = (const float*)d_in[7];

  int N = in_sizes[0] / FDIM;
  int E = in_sizes[1] / 2;

  char* p = (char*)d_ws;
  auto alloc = [&](size_t bytes) {
    char* r = p; p += (bytes + 255) & ~size_t(255); return r;
  };
  int*      counts  = (int*)alloc(sizeof(int) * N);
  int*      offsets = (int*)alloc(sizeof(int) * (N + 1));
  int*      bsum    = (int*)alloc(sizeof(int) * 256);
  int*      src32   = (int*)alloc(sizeof(int) * E);
  int*      dst32   = (int*)alloc(sizeof(int) * E);
  int*      rank    = (int*)alloc(sizeof(int) * E);
  int*      csr     = (int*)alloc(sizeof(int) * E);
  __half*   h16     = (__half*)alloc(sizeof(__half) * (size_t)N * FDIM);
  float*    rn      = (float*)alloc(sizeof(float) * N);
  __half*   y1h     = (__half*)alloc(sizeof(__half) * (size_t)N * FDIM);
  _Float16* wp1     = (_Float16*)alloc(sizeof(_Float16) * 2048 * 8);
  _Float16* wp2     = (_Float16*)alloc(sizeof(_Float16) * 2048 * 8);

  hipMemsetAsync(counts, 0, sizeof(int) * N, stream);
  pack_w_kernel<<<16, 256, 0, stream>>>(W1, W2, wp1, wp2);

  int cb  = (E + 511) / 512;                // convert: 2 edges/thread
  int gb  = (N + 63) / 64;                  // gemm: 64-row tiles
  int sb  = (E + 256 * SCAT_EPT - 1) / (256 * SCAT_EPT);
  int nb  = (N + SCAN_CHUNK - 1) / SCAN_CHUNK;
  int ab  = (N + 3) / 4;                    // agg: 4 waves/block

  // convert (atomic-latency wall) + gemm1 (MFMA) fused; convert blocks first
  convert_gemm1_kernel<<<cb + gb, 256, 0, stream>>>(
      ei, E, src32, dst32, rank, counts, cb, x, wp1, b1, h16, rn, N);
  scan_a_kernel<<<nb, 256, 0, stream>>>(counts, bsum, N);
  scan_c_kernel<<<nb, 256, 0, stream>>>(counts, bsum, offsets, N, E);
  scatter_kernel<<<sb, 256, 0, stream>>>(src32, dst32, rank, offsets, E, csr);

  agg_kernel<true><<<ab, 256, 0, stream>>>(h16, rn, beta1, offsets, csr, y1h, N);
  gemm2_kernel<<<gb, 256, 0, stream>>>(y1h, wp2, b2, h16, rn, N);
  agg_kernel<false><<<ab, 256, 0, stream>>>(h16, rn, beta2, offsets, csr, d_out, N);
}

// Round 9
// 217.312 us; speedup vs baseline: 1.2701x; 1.1002x over previous
//
#include <hip/hip_runtime.h>
#include <hip/hip_bf16.h>
#include <hip/hip_fp16.h>

// AGNN 2-layer encoder: N=50000 nodes, E=850000 edges (w/ self-loops), D=H=128.
// R9: CSR build via 8-bit-MSD bucket sort (LDS atomics only; the 850K global
// returning atomics were a ~43us device-wide RMW-throughput wall). Pipeline:
// hist_convert -> scan -> radix_scatter -> bucket_csr -> [MFMA gemm -> agg] x2.

#define FDIM 128
#define SCAN_CHUNK 2048   // elements per scan block (256 thr x 8)
#define K1_CHUNK 4096     // edges per histogram/scatter block (16/thread)

typedef _Float16 f16x8 __attribute__((ext_vector_type(8)));
typedef _Float16 f16x2 __attribute__((ext_vector_type(2)));
typedef float f32x4 __attribute__((ext_vector_type(4)));

#if defined(__has_builtin)
#if __has_builtin(__builtin_amdgcn_fdot2)
#define HAS_FDOT2 1
#endif
#endif

// ------- pack W (f32 [K=128][N=128]) into fp16 B-fragment layout -----------
// B frag for mfma_f32_16x16x32_f16: lane l holds B[kt*32+(l>>4)*8+j][nt*16+(l&15)].
__global__ __launch_bounds__(256) void pack_w_kernel(
    const float* __restrict__ W1, const float* __restrict__ W2,
    _Float16* __restrict__ wp1, _Float16* __restrict__ wp2) {
  int t = blockIdx.x * 256 + threadIdx.x;            // 0..4095
  const float* W = (t < 2048) ? W1 : W2;
  _Float16* wp   = (t < 2048) ? wp1 : wp2;
  int tt = t & 2047;
  int l = tt & 63, tile = tt >> 6, kt = tile & 3, nt = tile >> 2;
  int kbase = kt * 32 + (l >> 4) * 8, col = nt * 16 + (l & 15);
  f16x8 v;
  #pragma unroll
  for (int j = 0; j < 8; ++j) v[j] = (_Float16)W[(kbase + j) * 128 + col];
  *(f16x8*)(wp + (size_t)tt * 8) = v;
}

// ------- k1: convert edges -> (dst,src) pairs + per-block 256-bin hist -----
// bin = dst>>8 (bucket of 256 dst values). LDS atomics only.
__global__ __launch_bounds__(256) void hist_convert_kernel(
    const void* __restrict__ ei, int E, int NBINS, int NB1,
    int2* __restrict__ pairs0, int* __restrict__ g_hist) {
  __shared__ int hist[256];
  int tid = threadIdx.x;
  hist[tid] = 0;
  const int* eii = (const int*)ei;
  int lane = tid & 63;
  int ok = (lane < 32) ? (eii[2 * lane + 1] == 0) : 1;
  bool is64 = (__ballot(ok) == ~0ull);
  __syncthreads();
  int base = blockIdx.x * K1_CHUNK;
  for (int j = 0; j < 16; ++j) {
    int e = base + j * 256 + tid;
    if (e < E) {
      int s, d;
      if (is64) {
        const long long* p = (const long long*)ei;
        s = (int)p[e]; d = (int)p[(size_t)E + e];
      } else {
        s = eii[e]; d = eii[E + e];
      }
      pairs0[e] = make_int2(d, s);
      atomicAdd(&hist[d >> 8], 1);      // LDS atomic (CU-local, fast)
    }
  }
  __syncthreads();
  if (tid < NBINS) g_hist[tid * NB1 + blockIdx.x] = hist[tid];
}

// ------- scan stage A: per-chunk sums (generic, contiguous input) ----------
__global__ __launch_bounds__(256) void scan_a_kernel(
    const int* __restrict__ in, int* __restrict__ bsum, int L) {
  __shared__ int ws[4];
  int tid = threadIdx.x;
  int i0 = blockIdx.x * SCAN_CHUNK + tid * 8;
  int s = 0;
  if (i0 + 7 < L) {
    int4 a = *(const int4*)(in + i0);
    int4 b = *(const int4*)(in + i0 + 4);
    s = a.x + a.y + a.z + a.w + b.x + b.y + b.z + b.w;
  } else {
    #pragma unroll
    for (int j = 0; j < 8; ++j) if (i0 + j < L) s += in[i0 + j];
  }
  #pragma unroll
  for (int m = 32; m; m >>= 1) s += __shfl_xor(s, m);
  int lane = tid & 63, wv = tid >> 6;
  if (lane == 0) ws[wv] = s;
  __syncthreads();
  if (tid == 0) bsum[blockIdx.x] = ws[0] + ws[1] + ws[2] + ws[3];
}

// ------- scan stage C: per-chunk exclusive scan + cross-chunk base ---------
// Writes out[i] for i<L and out[L] = TOT.
__global__ __launch_bounds__(256) void scan_c_kernel(
    const int* __restrict__ in, const int* __restrict__ bsum,
    int* __restrict__ out, int L, int TOT) {
  __shared__ int wsum[4];
  int tid = threadIdx.x, lane = tid & 63, wv = tid >> 6;

  int bse = 0;
  for (int j = lane; j < (int)blockIdx.x; j += 64) bse += bsum[j];
  #pragma unroll
  for (int m = 32; m; m >>= 1) bse += __shfl_xor(bse, m);

  int i0 = blockIdx.x * SCAN_CHUNK + tid * 8;
  int v[8];
  if (i0 + 7 < L) {
    int4 a = *(const int4*)(in + i0);
    int4 b = *(const int4*)(in + i0 + 4);
    v[0]=a.x; v[1]=a.y; v[2]=a.z; v[3]=a.w;
    v[4]=b.x; v[5]=b.y; v[6]=b.z; v[7]=b.w;
  } else {
    #pragma unroll
    for (int j = 0; j < 8; ++j) v[j] = (i0 + j < L) ? in[i0 + j] : 0;
  }
  int pre[8], t = 0;
  #pragma unroll
  for (int j = 0; j < 8; ++j) { pre[j] = t; t += v[j]; }
  int x = t;
  #pragma unroll
  for (int off = 1; off < 64; off <<= 1) {
    int u = __shfl_up(x, off);
    if (lane >= off) x += u;
  }
  if (lane == 63) wsum[wv] = x;
  __syncthreads();
  int waveoff = 0;
  #pragma unroll
  for (int w = 0; w < 4; ++w) if (w < wv) waveoff += wsum[w];
  int ebase = bse + waveoff + (x - t);
  #pragma unroll
  for (int j = 0; j < 8; ++j) {
    int i = i0 + j;
    if (i < L) out[i] = ebase + pre[j];
  }
  if (blockIdx.x == 0 && tid == 0) out[L] = TOT;
}

// ------- k3: MSD scatter into 256-dst buckets (LDS cursors, race-free) -----
// Block blk owns segment [g_scan[bin*NB1+blk], +hist) within each bucket;
// MSD pass needs no stability -> LDS-atomic cursor order is fine.
__global__ __launch_bounds__(256) void radix_scatter_kernel(
    const int2* __restrict__ pairs0, const int* __restrict__ g_scan,
    int E, int NBINS, int NB1, int2* __restrict__ pairs1) {
  __shared__ int cur[256];
  int tid = threadIdx.x;
  if (tid < NBINS) cur[tid] = g_scan[tid * NB1 + blockIdx.x];
  __syncthreads();
  int base = blockIdx.x * K1_CHUNK;
  for (int j = 0; j < 16; ++j) {
    int e = base + j * 256 + tid;
    if (e < E) {
      int2 pr = pairs0[e];
      int pos = atomicAdd(&cur[pr.x >> 8], 1);
      pairs1[pos] = pr;
    }
  }
}

// ------- k4: per-bucket finalize: offsets[] + csr[] ------------------------
// One block per bucket (256 consecutive dst). LDS 256-bin hist of dst&255,
// in-block scan -> offsets; LDS cursor scatter -> csr (grouped by full dst).
__global__ __launch_bounds__(256) void bucket_csr_kernel(
    const int2* __restrict__ pairs1, const int* __restrict__ g_scan,
    int N, int NB1, int E, int* __restrict__ offsets, int* __restrict__ csr) {
  __shared__ int hist[256];
  __shared__ int cur[256];
  __shared__ int wsum[4];
  int tid = threadIdx.x, lane = tid & 63, wv = tid >> 6;
  int b = blockIdx.x;
  int segbase = g_scan[(size_t)b * NB1];
  int segend  = g_scan[(size_t)(b + 1) * NB1];
  hist[tid] = 0;
  __syncthreads();
  for (int i = segbase + tid; i < segend; i += 256)
    atomicAdd(&hist[pairs1[i].x & 255], 1);
  __syncthreads();
  int v = hist[tid];
  int x = v;
  #pragma unroll
  for (int off = 1; off < 64; off <<= 1) {
    int u = __shfl_up(x, off);
    if (lane >= off) x += u;
  }
  if (lane == 63) wsum[wv] = x;
  __syncthreads();
  int waveoff = 0;
  #pragma unroll
  for (int w = 0; w < 4; ++w) if (w < wv) waveoff += wsum[w];
  int excl = segbase + waveoff + (x - v);
  int dglob = b * 256 + tid;
  if (dglob < N) offsets[dglob] = excl;
  cur[tid] = excl;
  if (b == 0 && tid == 0) offsets[N] = E;
  __syncthreads();
  for (int i = segbase + tid; i < segend; i += 256) {
    int2 pr = pairs1[i];
    int pos = atomicAdd(&cur[pr.x & 255], 1);
    csr[pos] = pr.y;
  }
}

// ------- MFMA gemm body: H = X@W + b, fused row L2-norm, fp16 H out --------
// 64 rows/block, 4 waves. X staged fp16 in LDS [64][136]. C layout (m89):
// col=lane&15, row=(lane>>4)*4+reg.
template <typename TIN>
__device__ __forceinline__ void mfma_gemm_body(
    const TIN* __restrict__ X, const _Float16* __restrict__ wp,
    const float* __restrict__ bias, __half* __restrict__ H16,
    float* __restrict__ rnorm, int N, int bid) {
  __shared__ _Float16 xt[64][136];
  int tid = threadIdx.x;
  int l = tid & 63, wv = tid >> 6;
  int r0 = bid * 64;

  for (int idx = tid; idx < 64 * 16; idx += 256) {
    int row = idx >> 4, c8 = idx & 15;
    int r = r0 + row; if (r >= N) r = N - 1;
    f16x8 v;
    if constexpr (sizeof(TIN) == 4) {
      const float* px = (const float*)X + (size_t)r * 128 + c8 * 8;
      float4 a = *(const float4*)px;
      float4 b = *(const float4*)(px + 4);
      v[0]=(_Float16)a.x; v[1]=(_Float16)a.y; v[2]=(_Float16)a.z; v[3]=(_Float16)a.w;
      v[4]=(_Float16)b.x; v[5]=(_Float16)b.y; v[6]=(_Float16)b.z; v[7]=(_Float16)b.w;
    } else {
      v = *(const f16x8*)((const __half*)X + (size_t)r * 128 + c8 * 8);
    }
    *(f16x8*)&xt[row][c8 * 8] = v;
  }
  __syncthreads();

  f32x4 acc[8];
  #pragma unroll
  for (int nt = 0; nt < 8; ++nt) acc[nt] = (f32x4){0.f, 0.f, 0.f, 0.f};

  int arow = wv * 16 + (l & 15);
  int koff = (l >> 4) * 8;
  #pragma unroll
  for (int kt = 0; kt < 4; ++kt) {
    f16x8 afrag = *(const f16x8*)&xt[arow][kt * 32 + koff];
    #pragma unroll
    for (int nt = 0; nt < 8; ++nt) {
      f16x8 bfrag = *(const f16x8*)(wp + (size_t)((nt * 4 + kt) * 64 + l) * 8);
      acc[nt] = __builtin_amdgcn_mfma_f32_16x16x32_f16(afrag, bfrag, acc[nt], 0, 0, 0);
    }
  }

  int col = l & 15, g = l >> 4;
  float bv[8];
  #pragma unroll
  for (int nt = 0; nt < 8; ++nt) bv[nt] = bias[nt * 16 + col];

  #pragma unroll
  for (int j = 0; j < 4; ++j) {
    float hv[8]; float s = 0.f;
    #pragma unroll
    for (int nt = 0; nt < 8; ++nt) { hv[nt] = acc[nt][j] + bv[nt]; s += hv[nt] * hv[nt]; }
    s += __shfl_xor(s, 1); s += __shfl_xor(s, 2);
    s += __shfl_xor(s, 4); s += __shfl_xor(s, 8);   // 16-lane col group
    int r = r0 + wv * 16 + g * 4 + j;
    if (r < N) {
      #pragma unroll
      for (int nt = 0; nt < 8; ++nt)
        H16[(size_t)r * 128 + nt * 16 + col] = __float2half(hv[nt]);
      if (col == 0) rnorm[r] = rsqrtf(s + 1e-12f);
    }
  }
}

__global__ __launch_bounds__(256) void gemm1_kernel(
    const float* __restrict__ X, const _Float16* __restrict__ wp,
    const float* __restrict__ bias, __half* __restrict__ H16,
    float* __restrict__ rnorm, int N) {
  mfma_gemm_body<float>(X, wp, bias, H16, rnorm, N, blockIdx.x);
}

__global__ __launch_bounds__(256) void gemm2_kernel(
    const __half* __restrict__ X, const _Float16* __restrict__ wp,
    const float* __restrict__ bias, __half* __restrict__ H16,
    float* __restrict__ rnorm, int N) {
  mfma_gemm_body<__half>(X, wp, bias, H16, rnorm, N, blockIdx.x);
}

// ---------------- fused attention softmax + aggregate + relu ---------------
// One wave per dst node, 4 groups x 16 lanes; each group scores a different
// edge; sublane l holds dims 8l..8l+7 (one 16B fp16 gather per edge).
// Prefetch depth 2. Dot via v_dot2_f32_f16 (f32 accum) when available.
template <bool OUT_HALF>
__global__ __launch_bounds__(256) void agg_kernel(
    const __half* __restrict__ H16, const float* __restrict__ rnorm,
    const float* __restrict__ beta_p, const int* __restrict__ offsets,
    const int* __restrict__ csr_src, void* __restrict__ Yp, int N) {
  int wid = (blockIdx.x * 256 + threadIdx.x) >> 6;
  int lane = threadIdx.x & 63;
  if (wid >= N) return;
  int g = lane >> 4;
  int l = lane & 15;
  const float4* H4 = (const float4*)H16;

  float4 hdv = H4[(size_t)wid * 16 + l];
  const __half2* hdp = (const __half2*)&hdv;
  float2 d0 = __half22float2(hdp[0]);
  float2 d1 = __half22float2(hdp[1]);
  float2 d2 = __half22float2(hdp[2]);
  float2 d3 = __half22float2(hdp[3]);
  float rdb = rnorm[wid] * beta_p[0];

  int e0 = offsets[wid], e1 = offsets[wid + 1];
  float denom = 0.f;
  float acc[8] = {0.f,0.f,0.f,0.f,0.f,0.f,0.f,0.f};

  int eA = e0 + g;
  bool vA = eA < e1;
  int sA = vA ? csr_src[eA] : wid;
  float4 hA = H4[(size_t)sA * 16 + l];
  float rA = rnorm[sA];

  int eB = eA + 4;
  bool vB = eB < e1;
  int sB = vB ? csr_src[eB] : wid;
  float4 hB = H4[(size_t)sB * 16 + l];
  float rB = rnorm[sB];

  for (int eb = e0; eb < e1; eb += 4) {
    int eC = eb + 8 + g;
    bool vC = eC < e1;
    int sC = vC ? csr_src[eC] : wid;
    float4 hC = H4[(size_t)sC * 16 + l];
    float rC = rnorm[sC];

    const __half2* hp = (const __half2*)&hA;
    float2 q0 = __half22float2(hp[0]);
    float2 q1 = __half22float2(hp[1]);
    float2 q2 = __half22float2(hp[2]);
    float2 q3 = __half22float2(hp[3]);
#ifdef HAS_FDOT2
    const f16x2* ha2 = (const f16x2*)&hA;
    const f16x2* hd2 = (const f16x2*)&hdv;
    float p = 0.f;
    #pragma unroll
    for (int t = 0; t < 4; ++t) p = __builtin_amdgcn_fdot2(ha2[t], hd2[t], p, false);
#else
    float p = q0.x*d0.x + q0.y*d0.y + q1.x*d1.x + q1.y*d1.y
            + q2.x*d2.x + q2.y*d2.y + q3.x*d3.x + q3.y*d3.y;
#endif
    p += __shfl_xor(p, 1);
    p += __shfl_xor(p, 2);
    p += __shfl_xor(p, 4);
    p += __shfl_xor(p, 8);
    float w = vA ? __expf(p * rdb * rA) : 0.f;
    denom += w;
    acc[0] += w*q0.x; acc[1] += w*q0.y; acc[2] += w*q1.x; acc[3] += w*q1.y;
    acc[4] += w*q2.x; acc[5] += w*q2.y; acc[6] += w*q3.x; acc[7] += w*q3.y;

    vA = vB; hA = hB; rA = rB;
    vB = vC; hB = hC; rB = rC;
  }

  #pragma unroll
  for (int m = 16; m <= 32; m <<= 1) {
    denom += __shfl_xor(denom, m);
    #pragma unroll
    for (int j = 0; j < 8; ++j) acc[j] += __shfl_xor(acc[j], m);
  }
  if (g == 0) {
    float inv = 1.0f / denom;  // denom > 0 guaranteed by self-loop
    float o[8];
    #pragma unroll
    for (int j = 0; j < 8; ++j) o[j] = fmaxf(acc[j] * inv, 0.f);
    if constexpr (OUT_HALF) {
      float4 pack;
      __half2* hp2 = (__half2*)&pack;
      hp2[0] = __floats2half2_rn(o[0], o[1]);
      hp2[1] = __floats2half2_rn(o[2], o[3]);
      hp2[2] = __floats2half2_rn(o[4], o[5]);
      hp2[3] = __floats2half2_rn(o[6], o[7]);
      ((float4*)Yp)[(size_t)wid * 16 + l] = pack;
    } else {
      float4 o0 = {o[0], o[1], o[2], o[3]};
      float4 o1 = {o[4], o[5], o[6], o[7]};
      ((float4*)Yp)[(size_t)wid * 32 + 2 * l] = o0;
      ((float4*)Yp)[(size_t)wid * 32 + 2 * l + 1] = o1;
    }
  }
}

// ---------------- launcher -------------------------------------------------
extern "C" void kernel_launch(void* const* d_in, const int* in_sizes, int n_in,
                              void* d_out, int out_size, void* d_ws, size_t ws_size,
                              hipStream_t stream) {
  const float* x     = (const float*)d_in[0];
  const void*  ei    = d_in[1];
  const float* W1    = (const float*)d_in[2];
  const float* b1    = (const float*)d_in[3];
  const float* beta1 = (const float*)d_in[4];
  const float* W2    = (const float*)d_in[5];
  const float* b2    = (const float*)d_in[6];
  const float* beta2 = (const float*)d_in[7];

  int N = in_sizes[0] / FDIM;
  int E = in_sizes[1] / 2;

  int NBINS = (N + 255) / 256;              // dst buckets of 256 (196 here)
  int NB1   = (E + K1_CHUNK - 1) / K1_CHUNK; // hist/scatter blocks (208)
  int L2    = NBINS * NB1;                  // flattened hist length

  char* p = (char*)d_ws;
  auto alloc = [&](size_t bytes) {
    char* r = p; p += (bytes + 255) & ~size_t(255); return r;
  };
  int*      g_hist  = (int*)alloc(sizeof(int) * L2);
  int*      g_scan  = (int*)alloc(sizeof(int) * (L2 + 1));
  int*      bsum    = (int*)alloc(sizeof(int) * 64);
  int2*     pairs0  = (int2*)alloc(sizeof(int2) * E);
  int2*     pairs1  = (int2*)alloc(sizeof(int2) * E);
  int*      csr     = (int*)alloc(sizeof(int) * E);
  int*      offsets = (int*)alloc(sizeof(int) * (N + 1));
  __half*   h16     = (__half*)alloc(sizeof(__half) * (size_t)N * FDIM);
  float*    rn      = (float*)alloc(sizeof(float) * N);
  __half*   y1h     = (__half*)alloc(sizeof(__half) * (size_t)N * FDIM);
  _Float16* wp1     = (_Float16*)alloc(sizeof(_Float16) * 2048 * 8);
  _Float16* wp2     = (_Float16*)alloc(sizeof(_Float16) * 2048 * 8);

  int nb2 = (L2 + SCAN_CHUNK - 1) / SCAN_CHUNK;   // scan blocks (20)
  int gb  = (N + 63) / 64;                         // gemm tiles (782)
  int ab  = (N + 3) / 4;                           // agg blocks (4 waves ea)

  pack_w_kernel<<<16, 256, 0, stream>>>(W1, W2, wp1, wp2);
  hist_convert_kernel<<<NB1, 256, 0, stream>>>(ei, E, NBINS, NB1, pairs0, g_hist);
  scan_a_kernel<<<nb2, 256, 0, stream>>>(g_hist, bsum, L2);
  scan_c_kernel<<<nb2, 256, 0, stream>>>(g_hist, bsum, g_scan, L2, E);
  radix_scatter_kernel<<<NB1, 256, 0, stream>>>(pairs0, g_scan, E, NBINS, NB1, pairs1);
  bucket_csr_kernel<<<NBINS, 256, 0, stream>>>(pairs1, g_scan, N, NB1, E, offsets, csr);

  gemm1_kernel<<<gb, 256, 0, stream>>>(x, wp1, b1, h16, rn, N);
  agg_kernel<true><<<ab, 256, 0, stream>>>(h16, rn, beta1, offsets, csr, y1h, N);
  gemm2_kernel<<<gb, 256, 0, stream>>>(y1h, wp2, b2, h16, rn, N);
  agg_kernel<false><<<ab, 256, 0, stream>>>(h16, rn, beta2, offsets, csr, d_out, N);
}